// Round 17
// baseline (409.050 us; speedup 1.0000x reference)
//
#include <hip/hip_runtime.h>
#include <hip/hip_bf16.h>
#include <math.h>

#define TM 64      // nodes per ffn tile
#define XROW 64    // xs row = 64 bytes: 4 f32 (feat*dinv, pad) + 16 bf16 (emb*dinv) + 16B pad
#define NSEG 8     // CSR segments (one per XCD via bid&7)

typedef float v2f __attribute__((ext_vector_type(2)));
typedef float f32x4 __attribute__((ext_vector_type(4)));
typedef __bf16 bf16x8 __attribute__((ext_vector_type(8)));
typedef unsigned short u16x8 __attribute__((ext_vector_type(8)));
typedef unsigned int uint_t;
typedef unsigned short ushort_t;

__device__ __forceinline__ v2f fma2(v2f a, v2f b, v2f c) {
    return __builtin_elementwise_fma(a, b, c);
}
__device__ __forceinline__ v2f splat2(float s) { return (v2f){s, s}; }
__device__ __forceinline__ v2f max02(v2f a) {
    return (v2f){fmaxf(a.x, 0.0f), fmaxf(a.y, 0.0f)};
}
__device__ __forceinline__ uint_t pack_bf16(float lo, float hi) {
    uint_t r;
    asm volatile("v_cvt_pk_bf16_f32 %0, %1, %2" : "=v"(r) : "v"(lo), "v"(hi));
    return r;
}
__device__ __forceinline__ float bf16_f(ushort_t u) {
    union { uint_t i; float f; } c; c.i = ((uint_t)u) << 16; return c.f;
}
__device__ __forceinline__ float blo(uint_t u) {
    union { uint_t i; float f; } c; c.i = u << 16; return c.f;
}
__device__ __forceinline__ float bhi(uint_t u) {
    union { uint_t i; float f; } c; c.i = u & 0xffff0000u; return c.f;
}

// abuf byte address for (node, feat): [node][feat] bf16, XOR-swizzled 16B slots
__device__ __forceinline__ int aaddr(int node, int feat) {
    return (node * 256 + feat * 2) ^ ((node & 15) << 4);
}

// ---------------- weight pre-swizzle (3 layers) + prep (wb) in one launch ----------------
// blocks 0..383: swizzle fw1/fw2/fw3. block 384: wb = [cw2@ow, cb2@ow+ob].
__global__ void prepw3_kernel(const float* __restrict__ W1, const float* __restrict__ W2,
                              const float* __restrict__ W3, ushort_t* __restrict__ out,
                              const float* __restrict__ cw2, const float* __restrict__ cb2,
                              const float* __restrict__ ow, const float* __restrict__ ob,
                              float* __restrict__ wb) {
    if (blockIdx.x == 384) {
        int i = threadIdx.x;
        if (i < 64) {
            float a = 0.f;
            for (int j = 0; j < 64; j++) a += cw2[i * 64 + j] * ow[j];
            wb[i] = a;
        }
        if (i == 0) {
            float bb = 0.f;
            for (int j = 0; j < 64; j++) bb += cb2[j] * ow[j];
            wb[64] = bb + ob[0];
        }
        return;
    }
    int gid = blockIdx.x * 256 + threadIdx.x;      // 0 .. 3*32768-1
    int layer = gid >> 15;
    int idx   = gid & 32767;
    const float* W = (layer == 0) ? W1 : (layer == 1) ? W2 : W3;
    int j    = idx & 7;
    int lane = (idx >> 3) & 63;
    int rest = idx >> 9;
    int cb   = rest & 7;
    int r2   = rest >> 3;
    int kk   = r2 & 3;
    int h    = r2 >> 2;
    int k = kk * 32 + (lane >> 4) * 8 + j;
    int n = cb * 16 + (lane & 15);
    float wv = W[k * 128 + n];
    ushort_t hi = (ushort_t)pack_bf16(wv, wv);
    ushort_t v;
    if (h == 0) v = hi;
    else {
        float res = wv - bf16_f(hi);
        v = (ushort_t)pack_bf16(res, res);
    }
    out[(size_t)layer * 32768 + idx] = v;
}

// ---------------- fused FFN + decoder ----------------
// L0 scalar -> abuf; L1-3 MFMA (hi/lo bf16 weights); transpose -> tbuf;
// dw0 staged bf16 into dead abuf; D0 from LDS broadcast; D1/D2 scalar.
// LDS = 32768 exactly (ps1/ps2 aliased into tbuf) -> 5 blocks/CU.
__global__ __launch_bounds__(256, 5) void ffn_kernel(
    const float* __restrict__ coords, const float* __restrict__ features,
    const float* __restrict__ dinv,
    const float* __restrict__ fw0, const float* __restrict__ fb0,
    const float* __restrict__ fg0, const float* __restrict__ fe0,
    const ushort_t* __restrict__ wswz,
    const float* __restrict__ fb1, const float* __restrict__ fg1, const float* __restrict__ fe1,
    const float* __restrict__ fb2, const float* __restrict__ fg2, const float* __restrict__ fe2,
    const float* __restrict__ fb3,
    const float* __restrict__ dw0, const float* __restrict__ db0,
    const float* __restrict__ dw1, const float* __restrict__ db1,
    const float* __restrict__ dw2, const float* __restrict__ db2,
    char* __restrict__ xsb, int n_nodes)
{
    __shared__ __align__(16) char abuf[16384];    // [64 nodes][128 feats] bf16, swizzled; later dw0 bf16
    __shared__ __align__(16) ushort_t tbuf[128][64]; // decoder layout; L0 aliases ps1/ps2 here

    const int t    = threadIdx.x;
    const int lane = t & 63;
    const int w    = __builtin_amdgcn_readfirstlane(t >> 6);
    const int jw   = w * 32;
    const int n0   = blockIdx.x * TM;

    int g = n0 + lane;
    if (g >= n_nodes) g = n_nodes - 1;

    // ---- layer 0: 2 -> 128, relu, LN, write abuf (ps1/ps2 alias tbuf storage) ----
    {
        float* ps1 = (float*)tbuf;          // [4][64]
        float* ps2 = ((float*)tbuf) + 256;  // [4][64]
        v2f acc[16];
        float2 c = *(const float2*)&coords[(size_t)g * 2];
        v2f cx = splat2(c.x), cy = splat2(c.y);
        #pragma unroll
        for (int q = 0; q < 16; q++) {
            int j = jw + 2 * q;
            v2f w0 = *(const v2f*)&fw0[j];
            v2f w1 = *(const v2f*)&fw0[128 + j];
            v2f bb = *(const v2f*)&fb0[j];
            acc[q] = max02(fma2(cx, w0, fma2(cy, w1, bb)));
        }
        float s1 = 0.f, s2 = 0.f;
        #pragma unroll
        for (int q = 0; q < 16; q++) {
            s1 += acc[q].x + acc[q].y;
            s2 += acc[q].x * acc[q].x + acc[q].y * acc[q].y;
        }
        ps1[w * 64 + lane] = s1; ps2[w * 64 + lane] = s2;
        __syncthreads();
        float t1 = ps1[lane] + ps1[64 + lane] + ps1[128 + lane] + ps1[192 + lane];
        float t2 = ps2[lane] + ps2[64 + lane] + ps2[128 + lane] + ps2[192 + lane];
        float mean = t1 * (1.0f / 128.0f);
        float var  = t2 * (1.0f / 128.0f) - mean * mean;
        float inv  = rsqrtf(var + 1e-5f);
        v2f mean2 = splat2(mean), inv2 = splat2(inv);
        #pragma unroll
        for (int q = 0; q < 16; q++) {
            int j = jw + 2 * q;
            v2f gm = *(const v2f*)&fg0[j];
            v2f bt = *(const v2f*)&fe0[j];
            v2f o = fma2((acc[q] - mean2) * inv2, gm, bt);
            *(uint_t*)(abuf + aaddr(lane, j)) = pack_bf16(o.x, o.y);
        }
        __syncthreads();
    }

    // ---- MFMA 128->128 layer: abuf = relu(abuf @ W + b), in place ----
    auto mfma_layer = [&](const ushort_t* Wb, const float* __restrict__ bias) {
        f32x4 acc[2][4] = {};
        #pragma unroll
        for (int kk = 0; kk < 4; kk++) {
            bf16x8 B[2][2];
            #pragma unroll
            for (int cb2 = 0; cb2 < 2; cb2++) {
                int cb = 2 * w + cb2;
                #pragma unroll
                for (int h = 0; h < 2; h++) {
                    const ushort_t* p = Wb + (size_t)(((h * 4 + kk) * 8 + cb) * 64 + lane) * 8;
                    B[cb2][h] = *(const bf16x8*)p;
                }
            }
            #pragma unroll
            for (int rb = 0; rb < 4; rb++) {
                int node = rb * 16 + (lane & 15);
                bf16x8 A = *(const bf16x8*)(abuf + aaddr(node, kk * 32 + (lane >> 4) * 8));
                #pragma unroll
                for (int cb2 = 0; cb2 < 2; cb2++) {
                    acc[cb2][rb] = __builtin_amdgcn_mfma_f32_16x16x32_bf16(A, B[cb2][0], acc[cb2][rb], 0, 0, 0);
                    acc[cb2][rb] = __builtin_amdgcn_mfma_f32_16x16x32_bf16(A, B[cb2][1], acc[cb2][rb], 0, 0, 0);
                }
            }
        }
        __syncthreads();
        float bv0 = bias[jw + (lane & 15)];
        float bv1 = bias[jw + 16 + (lane & 15)];
        #pragma unroll
        for (int cb2 = 0; cb2 < 2; cb2++) {
            int col = jw + cb2 * 16 + (lane & 15);
            float bv = cb2 ? bv1 : bv0;
            #pragma unroll
            for (int rb = 0; rb < 4; rb++) {
                #pragma unroll
                for (int r = 0; r < 4; r++) {
                    float v = fmaxf(acc[cb2][rb][r] + bv, 0.0f);
                    int node = rb * 16 + (lane >> 4) * 4 + r;
                    *(ushort_t*)(abuf + aaddr(node, col)) = (ushort_t)pack_bf16(v, v);
                }
            }
        }
        __syncthreads();
    };

    // ---- per-node LN on abuf (4 threads per node), in place ----
    auto ln_pass = [&](const float* __restrict__ gam, const float* __restrict__ bet) {
        int node = t >> 2;
        int part = t & 3;
        float vals[32];
        float s1 = 0.f, s2 = 0.f;
        #pragma unroll
        for (int q = 0; q < 4; q++) {
            int f0 = part * 32 + q * 8;
            u16x8 u = *(const u16x8*)(abuf + aaddr(node, f0));
            #pragma unroll
            for (int i = 0; i < 8; i++) {
                float v = bf16_f(u[i]);
                vals[q * 8 + i] = v;
                s1 += v; s2 += v * v;
            }
        }
        s1 += __shfl_xor(s1, 1); s1 += __shfl_xor(s1, 2);
        s2 += __shfl_xor(s2, 1); s2 += __shfl_xor(s2, 2);
        float mean = s1 * (1.0f / 128.0f);
        float var  = s2 * (1.0f / 128.0f) - mean * mean;
        float inv  = rsqrtf(var + 1e-5f);
        #pragma unroll
        for (int q = 0; q < 4; q++) {
            int f0 = part * 32 + q * 8;
            uint_t ov[4];
            #pragma unroll
            for (int p = 0; p < 4; p++) {
                v2f gm = *(const v2f*)&gam[f0 + 2 * p];
                v2f bt = *(const v2f*)&bet[f0 + 2 * p];
                float a = (vals[q * 8 + 2 * p]     - mean) * inv * gm.x + bt.x;
                float b = (vals[q * 8 + 2 * p + 1] - mean) * inv * gm.y + bt.y;
                ov[p] = pack_bf16(a, b);
            }
            uint4 uv = make_uint4(ov[0], ov[1], ov[2], ov[3]);
            *(uint4*)(abuf + aaddr(node, f0)) = uv;
        }
        __syncthreads();
    };

    mfma_layer(wswz,         fb1); ln_pass(fg1, fe1);
    mfma_layer(wswz + 32768, fb2); ln_pass(fg2, fe2);
    mfma_layer(wswz + 65536, fb3);   // relu only

    // ---- transpose abuf -> tbuf [feat][node] ----
    {
        #pragma unroll
        for (int q = 0; q < 4; q++) {
            int f0 = jw + q * 8;
            u16x8 u = *(const u16x8*)(abuf + aaddr(lane, f0));
            #pragma unroll
            for (int i = 0; i < 8; i++) tbuf[f0 + i][lane] = u[i];
        }
        __syncthreads();
    }

    // ---- stage dw0 (128x64 f32) into dead abuf as bf16 row-major [k][j] ----
    {
        const float2* src = (const float2*)dw0;   // 4096 float2
        uint_t* dst = (uint_t*)abuf;              // 4096 uints (bf16 pairs)
        #pragma unroll
        for (int q = 0; q < 16; q++) {
            int i = q * 256 + t;
            float2 v = src[i];
            dst[i] = pack_bf16(v.x, v.y);
        }
        __syncthreads();
    }

    // ---- decoder D0: 128 -> 64, tanh; weights from LDS broadcast ----
    {
        const int j16 = w * 16;
        v2f d0[8];
        #pragma unroll
        for (int q = 0; q < 8; q++) d0[q] = *(const v2f*)&db0[j16 + 2 * q];
        const uint4* wd = (const uint4*)abuf;     // row = 8 uint4 (64 bf16)
        #pragma unroll 4
        for (int k = 0; k < 128; k++) {
            v2f av = splat2(bf16_f(tbuf[k][lane]));
            uint4 u0 = wd[k * 8 + w * 2];
            uint4 u1 = wd[k * 8 + w * 2 + 1];
            d0[0] = fma2(av, (v2f){blo(u0.x), bhi(u0.x)}, d0[0]);
            d0[1] = fma2(av, (v2f){blo(u0.y), bhi(u0.y)}, d0[1]);
            d0[2] = fma2(av, (v2f){blo(u0.z), bhi(u0.z)}, d0[2]);
            d0[3] = fma2(av, (v2f){blo(u0.w), bhi(u0.w)}, d0[3]);
            d0[4] = fma2(av, (v2f){blo(u1.x), bhi(u1.x)}, d0[4]);
            d0[5] = fma2(av, (v2f){blo(u1.y), bhi(u1.y)}, d0[5]);
            d0[6] = fma2(av, (v2f){blo(u1.z), bhi(u1.z)}, d0[6]);
            d0[7] = fma2(av, (v2f){blo(u1.w), bhi(u1.w)}, d0[7]);
        }
        #pragma unroll
        for (int q = 0; q < 8; q++) d0[q] = (v2f){tanhf(d0[q].x), tanhf(d0[q].y)};
        __syncthreads();
        #pragma unroll
        for (int q = 0; q < 8; q++) {
            uint_t r = pack_bf16(d0[q].x, d0[q].y);
            tbuf[j16 + 2 * q][lane]     = (ushort_t)r;
            tbuf[j16 + 2 * q + 1][lane] = (ushort_t)(r >> 16);
        }
        __syncthreads();
    }

    // ---- decoder D1: 64 -> 32, tanh (8 outs/wave) ----
    {
        const int j8 = w * 8;
        v2f d1[4];
        #pragma unroll
        for (int q = 0; q < 4; q++) d1[q] = *(const v2f*)&db1[j8 + 2 * q];
        #pragma unroll 4
        for (int k = 0; k < 64; k++) {
            v2f av = splat2(bf16_f(tbuf[k][lane]));
            const v2f* W2 = (const v2f*)(dw1 + k * 32 + j8);
            #pragma unroll
            for (int q = 0; q < 4; q++) d1[q] = fma2(av, W2[q], d1[q]);
        }
        #pragma unroll
        for (int q = 0; q < 4; q++) d1[q] = (v2f){tanhf(d1[q].x), tanhf(d1[q].y)};
        __syncthreads();
        #pragma unroll
        for (int q = 0; q < 4; q++) {
            uint_t r = pack_bf16(d1[q].x, d1[q].y);
            tbuf[j8 + 2 * q][lane]     = (ushort_t)r;
            tbuf[j8 + 2 * q + 1][lane] = (ushort_t)(r >> 16);
        }
        __syncthreads();
    }

    // ---- decoder D2: 32 -> 16, linear (4 outs/wave) ----
    {
        const int j4 = w * 4;
        v2f d2[2];
        #pragma unroll
        for (int q = 0; q < 2; q++) d2[q] = *(const v2f*)&db2[j4 + 2 * q];
        #pragma unroll 4
        for (int k = 0; k < 32; k++) {
            v2f av = splat2(bf16_f(tbuf[k][lane]));
            const v2f* W2 = (const v2f*)(dw2 + k * 16 + j4);
            d2[0] = fma2(av, W2[0], d2[0]);
            d2[1] = fma2(av, W2[1], d2[1]);
        }
        __syncthreads();
        #pragma unroll
        for (int q = 0; q < 2; q++) {
            uint_t r = pack_bf16(d2[q].x, d2[q].y);
            tbuf[j4 + 2 * q][lane]     = (ushort_t)r;
            tbuf[j4 + 2 * q + 1][lane] = (ushort_t)(r >> 16);
        }
        __syncthreads();
    }

    // ---- write xs row (64 B): [f0,f1,f2,0]*dinv f32 | emb0..15*dinv bf16 | pad ----
    {
        const int nn = t & 63;
        const int jg = t >> 6;
        int gg = n0 + nn;
        if (gg < n_nodes && jg < 3) {
            float dgg = dinv[gg];
            char* rp = xsb + (size_t)gg * XROW;
            if (jg == 0) {
                float4 f;
                f.x = features[(size_t)gg * 3 + 0] * dgg;
                f.y = features[(size_t)gg * 3 + 1] * dgg;
                f.z = features[(size_t)gg * 3 + 2] * dgg;
                f.w = 0.0f;
                *(float4*)rp = f;
            } else {
                int e0 = (jg - 1) * 8;
                uint_t u[4];
                #pragma unroll
                for (int p = 0; p < 4; p++) {
                    float lo = bf16_f(tbuf[e0 + 2 * p][nn]) * dgg;
                    float hi = bf16_f(tbuf[e0 + 2 * p + 1][nn]) * dgg;
                    u[p] = pack_bf16(lo, hi);
                }
                uint4 uv = make_uint4(u[0], u[1], u[2], u[3]);
                *(uint4*)(rp + 16 + (jg - 1) * 16) = uv;
            }
        }
    }
}

// ---------------- segmented CSR build (segment = blockIdx & 7) ----------------
__global__ void deg8_kernel(const int* __restrict__ row, int* __restrict__ cnt8,
                            int E_, int Nn) {
    int s = blockIdx.x & (NSEG - 1);
    int* cs = cnt8 + (size_t)s * Nn;
    int e4 = (blockIdx.x * blockDim.x + threadIdx.x) * 4;
    if (e4 + 3 < E_) {
        int4 r = *(const int4*)&row[e4];
        atomicAdd(&cs[r.x], 1); atomicAdd(&cs[r.y], 1);
        atomicAdd(&cs[r.z], 1); atomicAdd(&cs[r.w], 1);
    } else {
        for (int e = e4; e < E_; e++) atomicAdd(&cs[row[e]], 1);
    }
}

__global__ void scan1_kernel(const int* __restrict__ in, int* __restrict__ out,
                             int* __restrict__ bsum, int n) {
    __shared__ int tmp[256];
    int t = threadIdx.x, b = blockIdx.x;
    int base = b * 2048 + t * 8;
    int v[8]; int s = 0;
    #pragma unroll
    for (int q = 0; q < 8; q++) {
        int idx = base + q;
        v[q] = (idx < n) ? in[idx] : 0;
        s += v[q];
    }
    tmp[t] = s; __syncthreads();
    #pragma unroll
    for (int d = 1; d < 256; d <<= 1) {
        int add = (t >= d) ? tmp[t - d] : 0;
        __syncthreads();
        tmp[t] += add;
        __syncthreads();
    }
    int run = tmp[t] - s;
    #pragma unroll
    for (int q = 0; q < 8; q++) {
        int idx = base + q;
        if (idx < n) out[idx] = run;
        run += v[q];
    }
    if (t == 255) bsum[b] = tmp[t];
}

__global__ void scan2_kernel(int* __restrict__ bsum, int B) {
    __shared__ int tmp[512];
    int t = threadIdx.x;
    tmp[t] = (t < B) ? bsum[t] : 0; __syncthreads();
    #pragma unroll
    for (int d = 1; d < 512; d <<= 1) {
        int add = (t >= d) ? tmp[t - d] : 0;
        __syncthreads();
        tmp[t] += add;
        __syncthreads();
    }
    if (t < B) bsum[t] = tmp[t];
}

// scanfix + dinv fused
__global__ void scanfix_dinv_kernel(int* __restrict__ data, const int* __restrict__ bsum,
                                    const int* __restrict__ cnt8, float* __restrict__ dinv,
                                    int n, int Nn) {
    int i = blockIdx.x * 256 + threadIdx.x;
    if (i < n) {
        int b = i >> 11;
        if (b > 0) data[i] += bsum[b - 1];
    }
    if (i < Nn) {
        int s = 0;
        #pragma unroll
        for (int q = 0; q < NSEG; q++) s += cnt8[(size_t)q * Nn + i];
        dinv[i] = rsqrtf((float)s + 1.0f);
    }
}

__global__ void scatter_kernel(const int* __restrict__ row, const int* __restrict__ col,
                               int* __restrict__ fill8, int* __restrict__ es,
                               int E_, int Nn) {
    int s = blockIdx.x & (NSEG - 1);
    int* fs = fill8 + (size_t)s * Nn;
    int e4 = (blockIdx.x * blockDim.x + threadIdx.x) * 4;
    if (e4 + 3 < E_) {
        int4 r = *(const int4*)&row[e4];
        int4 c = *(const int4*)&col[e4];
        es[atomicAdd(&fs[r.x], 1)] = c.x;
        es[atomicAdd(&fs[r.y], 1)] = c.y;
        es[atomicAdd(&fs[r.z], 1)] = c.z;
        es[atomicAdd(&fs[r.w], 1)] = c.w;
    } else {
        for (int e = e4; e < E_; e++) {
            int p = atomicAdd(&fs[row[e]], 1);
            es[p] = col[e];
        }
    }
}

// octet per node: lane oc walks CSR segment oc [fill8-cnt8, fill8)
__global__ __launch_bounds__(256) void node1g_kernel(
    const int* __restrict__ fill8, const int* __restrict__ cnt8, const int* __restrict__ es,
    const float* __restrict__ dinv, const char* __restrict__ xsb,
    const float* __restrict__ cw1, const float* __restrict__ cb1,
    const float* __restrict__ wb, float* __restrict__ ss, int n)
{
    __shared__ float w[19 * 64];
    __shared__ float bbs[64];
    __shared__ float wes[64];
    for (int i = threadIdx.x; i < 19 * 64; i += 256) w[i] = cw1[i];
    for (int i = threadIdx.x; i < 64; i += 256) { bbs[i] = cb1[i]; wes[i] = wb[i]; }
    __syncthreads();
    const int t  = threadIdx.x;
    const int oc = t & 7;
    const int i  = blockIdx.x * 32 + (t >> 3);
    if (i >= n) return;
    const float di = dinv[i];

    float af[19];
    #pragma unroll
    for (int q = 0; q < 19; q++) af[q] = 0.f;

    auto addrow = [&](const char* rp) {
        float4 F = *(const float4*)rp;
        uint4 U0 = *(const uint4*)(rp + 16);
        uint4 U1 = *(const uint4*)(rp + 32);
        af[0] += F.x; af[1] += F.y; af[2] += F.z;
        af[3]  += blo(U0.x); af[4]  += bhi(U0.x);
        af[5]  += blo(U0.y); af[6]  += bhi(U0.y);
        af[7]  += blo(U0.z); af[8]  += bhi(U0.z);
        af[9]  += blo(U0.w); af[10] += bhi(U0.w);
        af[11] += blo(U1.x); af[12] += bhi(U1.x);
        af[13] += blo(U1.y); af[14] += bhi(U1.y);
        af[15] += blo(U1.z); af[16] += bhi(U1.z);
        af[17] += blo(U1.w); af[18] += bhi(U1.w);
    };

    if (oc == 0) addrow(xsb + (size_t)i * XROW);
    const int end = fill8[(size_t)oc * n + i];
    const int dgs = cnt8[(size_t)oc * n + i];
    for (int e = end - dgs; e < end; e++) {
        int c = es[e];
        addrow(xsb + (size_t)c * XROW);
    }

    float a19[19];
    #pragma unroll
    for (int q = 0; q < 19; q++) {
        float v = af[q];
        v += __shfl_xor(v, 1);
        v += __shfl_xor(v, 2);
        v += __shfl_xor(v, 4);
        a19[q] = v * di;
    }

    const int j0 = oc * 8;
    v2f am[4];
    const v2f* w2  = (const v2f*)w;
    const v2f* bb2 = (const v2f*)bbs;
    #pragma unroll
    for (int q = 0; q < 4; q++) am[q] = bb2[j0 / 2 + q];
    #pragma unroll
    for (int k = 0; k < 19; k++) {
        v2f v = splat2(a19[k]);
        #pragma unroll
        for (int q = 0; q < 4; q++) am[q] = fma2(v, w2[k * 32 + j0 / 2 + q], am[q]);
    }
    const v2f* we2 = (const v2f*)wes;
    v2f sv2 = {0.f, 0.f};
    #pragma unroll
    for (int q = 0; q < 4; q++) sv2 = fma2(max02(am[q]), we2[j0 / 2 + q], sv2);
    float sv = sv2.x + sv2.y;
    sv += __shfl_xor(sv, 1);
    sv += __shfl_xor(sv, 2);
    sv += __shfl_xor(sv, 4);
    if (oc == 0) ss[i] = di * sv;
}

// octet per node: out[i] = b_eff + di * (ss[i] + sum ss[c])
__global__ __launch_bounds__(256) void outg_kernel(
    const int* __restrict__ fill8, const int* __restrict__ cnt8, const int* __restrict__ es,
    const float* __restrict__ dinv, const float* __restrict__ ss,
    const float* __restrict__ wb, float* __restrict__ out, int n)
{
    const int t  = threadIdx.x;
    const int oc = t & 7;
    const int i  = blockIdx.x * 32 + (t >> 3);
    if (i >= n) return;
    const int end = fill8[(size_t)oc * n + i];
    const int dgs = cnt8[(size_t)oc * n + i];
    float sum = (oc == 0) ? ss[i] : 0.f;
    for (int e = end - dgs; e < end; e++) {
        int c = es[e];
        sum += ss[c];
    }
    sum += __shfl_xor(sum, 1);
    sum += __shfl_xor(sum, 2);
    sum += __shfl_xor(sum, 4);
    if (oc == 0) out[i] = wb[64] + dinv[i] * sum;
}

extern "C" void kernel_launch(void* const* d_in, const int* in_sizes, int n_in,
                              void* d_out, int out_size, void* d_ws, size_t ws_size,
                              hipStream_t stream) {
    const float* coords   = (const float*)d_in[0];
    const float* features = (const float*)d_in[1];
    const int*   eidx     = (const int*)d_in[2];
    const float* fw0 = (const float*)d_in[3];
    const float* fb0 = (const float*)d_in[4];
    const float* fg0 = (const float*)d_in[5];
    const float* fe0 = (const float*)d_in[6];
    const float* fw1 = (const float*)d_in[7];
    const float* fb1 = (const float*)d_in[8];
    const float* fg1 = (const float*)d_in[9];
    const float* fe1 = (const float*)d_in[10];
    const float* fw2 = (const float*)d_in[11];
    const float* fb2 = (const float*)d_in[12];
    const float* fg2 = (const float*)d_in[13];
    const float* fe2 = (const float*)d_in[14];
    const float* fw3 = (const float*)d_in[15];
    const float* fb3 = (const float*)d_in[16];
    const float* dw0 = (const float*)d_in[17];
    const float* db0 = (const float*)d_in[18];
    const float* dw1 = (const float*)d_in[19];
    const float* db1 = (const float*)d_in[20];
    const float* dw2 = (const float*)d_in[21];
    const float* db2 = (const float*)d_in[22];
    const float* cw1 = (const float*)d_in[23];
    const float* cb1 = (const float*)d_in[24];
    const float* cw2 = (const float*)d_in[25];
    const float* cb2 = (const float*)d_in[26];
    const float* ow  = (const float*)d_in[27];
    const float* ob  = (const float*)d_in[28];
    float* out = (float*)d_out;

    const int Nn = in_sizes[0] / 2;   // 100000
    const int E_ = in_sizes[2] / 2;   // 2000000
    const int n8 = NSEG * Nn;
    const int NBS = (n8 + 2047) / 2048;
    const int NO = (Nn * 8 + 255) / 256;
    const int NT = (Nn + TM - 1) / TM;
    const int NE = (E_ / 4 + 255) / 256;

    char* ws = (char*)d_ws;
    size_t o = 0;
    char*  xsb   = (char*) (ws + o); o += (size_t)Nn * XROW;
    int*   cnt8  = (int*)  (ws + o); o += (size_t)n8 * sizeof(int);
    int*   fill8 = (int*)  (ws + o); o += (size_t)n8 * sizeof(int);
    int*   bsum  = (int*)  (ws + o); o += 512 * sizeof(int);
    float* dinv  = (float*)(ws + o); o += (size_t)Nn * sizeof(float);
    float* ssb   = (float*)(ws + o); o += (size_t)Nn * sizeof(float);
    int*   es    = (int*)  (ws + o); o += (size_t)E_ * sizeof(int);
    float* wb    = (float*)(ws + o); o += 80 * sizeof(float);
    o = (o + 15) & ~(size_t)15;
    ushort_t* wswz = (ushort_t*)(ws + o); o += 3 * 32768 * sizeof(ushort_t);

    hipMemsetAsync(cnt8, 0, (size_t)n8 * sizeof(int), stream);

    // weight pre-swizzle (3 layers) + wb prep, one launch
    prepw3_kernel<<<385, 256, 0, stream>>>(fw1, fw2, fw3, wswz, cw2, cb2, ow, ob, wb);

    // segmented CSR build
    deg8_kernel<<<NE, 256, 0, stream>>>(eidx, cnt8, E_, Nn);
    scan1_kernel<<<NBS, 256, 0, stream>>>(cnt8, fill8, bsum, n8);
    scan2_kernel<<<1, 512, 0, stream>>>(bsum, NBS);
    scanfix_dinv_kernel<<<(n8 + 255) / 256, 256, 0, stream>>>(fill8, bsum, cnt8, dinv, n8, Nn);
    scatter_kernel<<<NE, 256, 0, stream>>>(eidx, eidx + E_, fill8, es, E_, Nn);

    ffn_kernel<<<NT, 256, 0, stream>>>(
        coords, features, dinv,
        fw0, fb0, fg0, fe0,
        wswz,
        fb1, fg1, fe1, fb2, fg2, fe2, fb3,
        dw0, db0,
        dw1, db1, dw2, db2, xsb, Nn);

    node1g_kernel<<<NO, 256, 0, stream>>>(fill8, cnt8, es, dinv, xsb, cw1, cb1, wb, ssb, Nn);
    outg_kernel<<<NO, 256, 0, stream>>>(fill8, cnt8, es, dinv, ssb, wb, out, Nn);
}

// Round 18
// 374.160 us; speedup vs baseline: 1.0932x; 1.0932x over previous
//
#include <hip/hip_runtime.h>
#include <hip/hip_bf16.h>
#include <math.h>

#define TM 64      // nodes per ffn tile
#define XROW 64    // xs row = 64 bytes: 4 f32 (feat*dinv, pad) + 16 bf16 (emb*dinv) + 16B pad
#define NSEG 8     // CSR segments (one per XCD via bid&7)

typedef float v2f __attribute__((ext_vector_type(2)));
typedef float f32x4 __attribute__((ext_vector_type(4)));
typedef __bf16 bf16x8 __attribute__((ext_vector_type(8)));
typedef unsigned short u16x8 __attribute__((ext_vector_type(8)));
typedef unsigned int uint_t;
typedef unsigned short ushort_t;

__device__ __forceinline__ v2f fma2(v2f a, v2f b, v2f c) {
    return __builtin_elementwise_fma(a, b, c);
}
__device__ __forceinline__ v2f splat2(float s) { return (v2f){s, s}; }
__device__ __forceinline__ v2f max02(v2f a) {
    return (v2f){fmaxf(a.x, 0.0f), fmaxf(a.y, 0.0f)};
}
__device__ __forceinline__ uint_t pack_bf16(float lo, float hi) {
    uint_t r;
    asm volatile("v_cvt_pk_bf16_f32 %0, %1, %2" : "=v"(r) : "v"(lo), "v"(hi));
    return r;
}
__device__ __forceinline__ float bf16_f(ushort_t u) {
    union { uint_t i; float f; } c; c.i = ((uint_t)u) << 16; return c.f;
}
__device__ __forceinline__ float blo(uint_t u) {
    union { uint_t i; float f; } c; c.i = u << 16; return c.f;
}
__device__ __forceinline__ float bhi(uint_t u) {
    union { uint_t i; float f; } c; c.i = u & 0xffff0000u; return c.f;
}

// abuf byte address for (node, feat): [node][feat] bf16, XOR-swizzled 16B slots
__device__ __forceinline__ int aaddr(int node, int feat) {
    return (node * 256 + feat * 2) ^ ((node & 15) << 4);
}

// ---------------- fused: deg8 (blocks [0,NE)) + weight pre-swizzle/wb (blocks [NE, NE+385)) ----------------
__global__ void deg8_prep_kernel(const int* __restrict__ row, int* __restrict__ cnt8,
                                 int E_, int Nn, int NE,
                                 const float* __restrict__ W1, const float* __restrict__ W2,
                                 const float* __restrict__ W3, ushort_t* __restrict__ outw,
                                 const float* __restrict__ cw2, const float* __restrict__ cb2,
                                 const float* __restrict__ ow, const float* __restrict__ ob,
                                 float* __restrict__ wb) {
    int bid = blockIdx.x;
    if (bid < NE) {
        // deg8: segment = bid & 7 (must match scatter's mapping)
        int s = bid & (NSEG - 1);
        int* cs = cnt8 + (size_t)s * Nn;
        int e4 = (bid * 256 + threadIdx.x) * 4;
        if (e4 + 3 < E_) {
            int4 r = *(const int4*)&row[e4];
            atomicAdd(&cs[r.x], 1); atomicAdd(&cs[r.y], 1);
            atomicAdd(&cs[r.z], 1); atomicAdd(&cs[r.w], 1);
        } else {
            for (int e = e4; e < E_; e++) atomicAdd(&cs[row[e]], 1);
        }
        return;
    }
    int pid = bid - NE;
    if (pid == 384) {
        int i = threadIdx.x;
        if (i < 64) {
            float a = 0.f;
            for (int j = 0; j < 64; j++) a += cw2[i * 64 + j] * ow[j];
            wb[i] = a;
        }
        if (i == 0) {
            float bb = 0.f;
            for (int j = 0; j < 64; j++) bb += cb2[j] * ow[j];
            wb[64] = bb + ob[0];
        }
        return;
    }
    int gid = pid * 256 + threadIdx.x;      // 0 .. 3*32768-1
    int layer = gid >> 15;
    int idx   = gid & 32767;
    const float* W = (layer == 0) ? W1 : (layer == 1) ? W2 : W3;
    int j    = idx & 7;
    int lane = (idx >> 3) & 63;
    int rest = idx >> 9;
    int cb   = rest & 7;
    int r2   = rest >> 3;
    int kk   = r2 & 3;
    int h    = r2 >> 2;
    int k = kk * 32 + (lane >> 4) * 8 + j;
    int n = cb * 16 + (lane & 15);
    float wv = W[k * 128 + n];
    ushort_t hi = (ushort_t)pack_bf16(wv, wv);
    ushort_t v;
    if (h == 0) v = hi;
    else {
        float res = wv - bf16_f(hi);
        v = (ushort_t)pack_bf16(res, res);
    }
    outw[(size_t)layer * 32768 + idx] = v;
}

// ---------------- fused: scatter (blocks [0,NE)) + FFN (blocks [NE, NE+NT)) ----------------
// Scatter chunk = bid (same edge->segment map as deg8). FFN tile = bid - NE.
// FFN: L0 scalar -> abuf; L1-3 MFMA (hi/lo bf16); transpose -> tbuf; dw0 staged in dead abuf;
// D0 LDS-broadcast; D1/D2 scalar. LDS 32768, 4 blocks/CU (the empirically optimal residency).
__global__ __launch_bounds__(256, 4) void scatter_ffn_kernel(
    const int* __restrict__ row, const int* __restrict__ col,
    int* __restrict__ fill8, int* __restrict__ es, int E_, int NE,
    const float* __restrict__ coords, const float* __restrict__ features,
    const float* __restrict__ dinv,
    const float* __restrict__ fw0, const float* __restrict__ fb0,
    const float* __restrict__ fg0, const float* __restrict__ fe0,
    const ushort_t* __restrict__ wswz,
    const float* __restrict__ fb1, const float* __restrict__ fg1, const float* __restrict__ fe1,
    const float* __restrict__ fb2, const float* __restrict__ fg2, const float* __restrict__ fe2,
    const float* __restrict__ fb3,
    const float* __restrict__ dw0, const float* __restrict__ db0,
    const float* __restrict__ dw1, const float* __restrict__ db1,
    const float* __restrict__ dw2, const float* __restrict__ db2,
    char* __restrict__ xsb, int n_nodes)
{
    __shared__ __align__(16) char abuf[16384];
    __shared__ __align__(16) ushort_t tbuf[128][64];

    const int bid = blockIdx.x;
    const int t   = threadIdx.x;

    if (bid < NE) {
        // ---- scatter: segment = bid & 7 (single-XCD-owned es lines) ----
        int s = bid & (NSEG - 1);
        int Nn = n_nodes;
        int* fs = fill8 + (size_t)s * Nn;
        int e4 = (bid * 256 + t) * 4;
        if (e4 + 3 < E_) {
            int4 r = *(const int4*)&row[e4];
            int4 c = *(const int4*)&col[e4];
            es[atomicAdd(&fs[r.x], 1)] = c.x;
            es[atomicAdd(&fs[r.y], 1)] = c.y;
            es[atomicAdd(&fs[r.z], 1)] = c.z;
            es[atomicAdd(&fs[r.w], 1)] = c.w;
        } else {
            for (int e = e4; e < E_; e++) {
                int p = atomicAdd(&fs[row[e]], 1);
                es[p] = col[e];
            }
        }
        return;
    }

    const int lane = t & 63;
    const int w    = __builtin_amdgcn_readfirstlane(t >> 6);
    const int jw   = w * 32;
    const int n0   = (bid - NE) * TM;

    int g = n0 + lane;
    if (g >= n_nodes) g = n_nodes - 1;

    // ---- layer 0: 2 -> 128, relu, LN, write abuf (ps1/ps2 alias tbuf storage) ----
    {
        float* ps1 = (float*)tbuf;          // [4][64]
        float* ps2 = ((float*)tbuf) + 256;  // [4][64]
        v2f acc[16];
        float2 c = *(const float2*)&coords[(size_t)g * 2];
        v2f cx = splat2(c.x), cy = splat2(c.y);
        #pragma unroll
        for (int q = 0; q < 16; q++) {
            int j = jw + 2 * q;
            v2f w0 = *(const v2f*)&fw0[j];
            v2f w1 = *(const v2f*)&fw0[128 + j];
            v2f bb = *(const v2f*)&fb0[j];
            acc[q] = max02(fma2(cx, w0, fma2(cy, w1, bb)));
        }
        float s1 = 0.f, s2 = 0.f;
        #pragma unroll
        for (int q = 0; q < 16; q++) {
            s1 += acc[q].x + acc[q].y;
            s2 += acc[q].x * acc[q].x + acc[q].y * acc[q].y;
        }
        ps1[w * 64 + lane] = s1; ps2[w * 64 + lane] = s2;
        __syncthreads();
        float t1 = ps1[lane] + ps1[64 + lane] + ps1[128 + lane] + ps1[192 + lane];
        float t2 = ps2[lane] + ps2[64 + lane] + ps2[128 + lane] + ps2[192 + lane];
        float mean = t1 * (1.0f / 128.0f);
        float var  = t2 * (1.0f / 128.0f) - mean * mean;
        float inv  = rsqrtf(var + 1e-5f);
        v2f mean2 = splat2(mean), inv2 = splat2(inv);
        #pragma unroll
        for (int q = 0; q < 16; q++) {
            int j = jw + 2 * q;
            v2f gm = *(const v2f*)&fg0[j];
            v2f bt = *(const v2f*)&fe0[j];
            v2f o = fma2((acc[q] - mean2) * inv2, gm, bt);
            *(uint_t*)(abuf + aaddr(lane, j)) = pack_bf16(o.x, o.y);
        }
        __syncthreads();
    }

    // ---- MFMA 128->128 layer: abuf = relu(abuf @ W + b), in place ----
    auto mfma_layer = [&](const ushort_t* Wb, const float* __restrict__ bias) {
        f32x4 acc[2][4] = {};
        #pragma unroll
        for (int kk = 0; kk < 4; kk++) {
            bf16x8 B[2][2];
            #pragma unroll
            for (int cb2 = 0; cb2 < 2; cb2++) {
                int cb = 2 * w + cb2;
                #pragma unroll
                for (int h = 0; h < 2; h++) {
                    const ushort_t* p = Wb + (size_t)(((h * 4 + kk) * 8 + cb) * 64 + lane) * 8;
                    B[cb2][h] = *(const bf16x8*)p;
                }
            }
            #pragma unroll
            for (int rb = 0; rb < 4; rb++) {
                int node = rb * 16 + (lane & 15);
                bf16x8 A = *(const bf16x8*)(abuf + aaddr(node, kk * 32 + (lane >> 4) * 8));
                #pragma unroll
                for (int cb2 = 0; cb2 < 2; cb2++) {
                    acc[cb2][rb] = __builtin_amdgcn_mfma_f32_16x16x32_bf16(A, B[cb2][0], acc[cb2][rb], 0, 0, 0);
                    acc[cb2][rb] = __builtin_amdgcn_mfma_f32_16x16x32_bf16(A, B[cb2][1], acc[cb2][rb], 0, 0, 0);
                }
            }
        }
        __syncthreads();
        float bv0 = bias[jw + (lane & 15)];
        float bv1 = bias[jw + 16 + (lane & 15)];
        #pragma unroll
        for (int cb2 = 0; cb2 < 2; cb2++) {
            int col2 = jw + cb2 * 16 + (lane & 15);
            float bv = cb2 ? bv1 : bv0;
            #pragma unroll
            for (int rb = 0; rb < 4; rb++) {
                #pragma unroll
                for (int r = 0; r < 4; r++) {
                    float v = fmaxf(acc[cb2][rb][r] + bv, 0.0f);
                    int node = rb * 16 + (lane >> 4) * 4 + r;
                    *(ushort_t*)(abuf + aaddr(node, col2)) = (ushort_t)pack_bf16(v, v);
                }
            }
        }
        __syncthreads();
    };

    // ---- per-node LN on abuf (4 threads per node), in place ----
    auto ln_pass = [&](const float* __restrict__ gam, const float* __restrict__ bet) {
        int node = t >> 2;
        int part = t & 3;
        float vals[32];
        float s1 = 0.f, s2 = 0.f;
        #pragma unroll
        for (int q = 0; q < 4; q++) {
            int f0 = part * 32 + q * 8;
            u16x8 u = *(const u16x8*)(abuf + aaddr(node, f0));
            #pragma unroll
            for (int i = 0; i < 8; i++) {
                float v = bf16_f(u[i]);
                vals[q * 8 + i] = v;
                s1 += v; s2 += v * v;
            }
        }
        s1 += __shfl_xor(s1, 1); s1 += __shfl_xor(s1, 2);
        s2 += __shfl_xor(s2, 1); s2 += __shfl_xor(s2, 2);
        float mean = s1 * (1.0f / 128.0f);
        float var  = s2 * (1.0f / 128.0f) - mean * mean;
        float inv  = rsqrtf(var + 1e-5f);
        #pragma unroll
        for (int q = 0; q < 4; q++) {
            int f0 = part * 32 + q * 8;
            uint_t ov[4];
            #pragma unroll
            for (int p = 0; p < 4; p++) {
                v2f gm = *(const v2f*)&gam[f0 + 2 * p];
                v2f bt = *(const v2f*)&bet[f0 + 2 * p];
                float a = (vals[q * 8 + 2 * p]     - mean) * inv * gm.x + bt.x;
                float b = (vals[q * 8 + 2 * p + 1] - mean) * inv * gm.y + bt.y;
                ov[p] = pack_bf16(a, b);
            }
            uint4 uv = make_uint4(ov[0], ov[1], ov[2], ov[3]);
            *(uint4*)(abuf + aaddr(node, f0)) = uv;
        }
        __syncthreads();
    };

    mfma_layer(wswz,         fb1); ln_pass(fg1, fe1);
    mfma_layer(wswz + 32768, fb2); ln_pass(fg2, fe2);
    mfma_layer(wswz + 65536, fb3);   // relu only

    // ---- transpose abuf -> tbuf [feat][node] ----
    {
        #pragma unroll
        for (int q = 0; q < 4; q++) {
            int f0 = jw + q * 8;
            u16x8 u = *(const u16x8*)(abuf + aaddr(lane, f0));
            #pragma unroll
            for (int i = 0; i < 8; i++) tbuf[f0 + i][lane] = u[i];
        }
        __syncthreads();
    }

    // ---- stage dw0 (128x64 f32) into dead abuf as bf16 row-major [k][j] ----
    {
        const float2* src = (const float2*)dw0;
        uint_t* dst = (uint_t*)abuf;
        #pragma unroll
        for (int q = 0; q < 16; q++) {
            int i = q * 256 + t;
            float2 v = src[i];
            dst[i] = pack_bf16(v.x, v.y);
        }
        __syncthreads();
    }

    // ---- decoder D0: 128 -> 64, tanh; weights from LDS broadcast ----
    {
        const int j16 = w * 16;
        v2f d0[8];
        #pragma unroll
        for (int q = 0; q < 8; q++) d0[q] = *(const v2f*)&db0[j16 + 2 * q];
        const uint4* wd = (const uint4*)abuf;
        #pragma unroll 4
        for (int k = 0; k < 128; k++) {
            v2f av = splat2(bf16_f(tbuf[k][lane]));
            uint4 u0 = wd[k * 8 + w * 2];
            uint4 u1 = wd[k * 8 + w * 2 + 1];
            d0[0] = fma2(av, (v2f){blo(u0.x), bhi(u0.x)}, d0[0]);
            d0[1] = fma2(av, (v2f){blo(u0.y), bhi(u0.y)}, d0[1]);
            d0[2] = fma2(av, (v2f){blo(u0.z), bhi(u0.z)}, d0[2]);
            d0[3] = fma2(av, (v2f){blo(u0.w), bhi(u0.w)}, d0[3]);
            d0[4] = fma2(av, (v2f){blo(u1.x), bhi(u1.x)}, d0[4]);
            d0[5] = fma2(av, (v2f){blo(u1.y), bhi(u1.y)}, d0[5]);
            d0[6] = fma2(av, (v2f){blo(u1.z), bhi(u1.z)}, d0[6]);
            d0[7] = fma2(av, (v2f){blo(u1.w), bhi(u1.w)}, d0[7]);
        }
        #pragma unroll
        for (int q = 0; q < 8; q++) d0[q] = (v2f){tanhf(d0[q].x), tanhf(d0[q].y)};
        __syncthreads();
        #pragma unroll
        for (int q = 0; q < 8; q++) {
            uint_t r = pack_bf16(d0[q].x, d0[q].y);
            tbuf[j16 + 2 * q][lane]     = (ushort_t)r;
            tbuf[j16 + 2 * q + 1][lane] = (ushort_t)(r >> 16);
        }
        __syncthreads();
    }

    // ---- decoder D1: 64 -> 32, tanh (8 outs/wave) ----
    {
        const int j8 = w * 8;
        v2f d1[4];
        #pragma unroll
        for (int q = 0; q < 4; q++) d1[q] = *(const v2f*)&db1[j8 + 2 * q];
        #pragma unroll 4
        for (int k = 0; k < 64; k++) {
            v2f av = splat2(bf16_f(tbuf[k][lane]));
            const v2f* W2 = (const v2f*)(dw1 + k * 32 + j8);
            #pragma unroll
            for (int q = 0; q < 4; q++) d1[q] = fma2(av, W2[q], d1[q]);
        }
        #pragma unroll
        for (int q = 0; q < 4; q++) d1[q] = (v2f){tanhf(d1[q].x), tanhf(d1[q].y)};
        __syncthreads();
        #pragma unroll
        for (int q = 0; q < 4; q++) {
            uint_t r = pack_bf16(d1[q].x, d1[q].y);
            tbuf[j8 + 2 * q][lane]     = (ushort_t)r;
            tbuf[j8 + 2 * q + 1][lane] = (ushort_t)(r >> 16);
        }
        __syncthreads();
    }

    // ---- decoder D2: 32 -> 16, linear (4 outs/wave) ----
    {
        const int j4 = w * 4;
        v2f d2[2];
        #pragma unroll
        for (int q = 0; q < 2; q++) d2[q] = *(const v2f*)&db2[j4 + 2 * q];
        #pragma unroll 4
        for (int k = 0; k < 32; k++) {
            v2f av = splat2(bf16_f(tbuf[k][lane]));
            const v2f* W2 = (const v2f*)(dw2 + k * 16 + j4);
            d2[0] = fma2(av, W2[0], d2[0]);
            d2[1] = fma2(av, W2[1], d2[1]);
        }
        __syncthreads();
        #pragma unroll
        for (int q = 0; q < 2; q++) {
            uint_t r = pack_bf16(d2[q].x, d2[q].y);
            tbuf[j4 + 2 * q][lane]     = (ushort_t)r;
            tbuf[j4 + 2 * q + 1][lane] = (ushort_t)(r >> 16);
        }
        __syncthreads();
    }

    // ---- write xs row (64 B): [f0,f1,f2,0]*dinv f32 | emb0..15*dinv bf16 | pad ----
    {
        const int nn = t & 63;
        const int jg = t >> 6;
        int gg = n0 + nn;
        if (gg < n_nodes && jg < 3) {
            float dgg = dinv[gg];
            char* rp = xsb + (size_t)gg * XROW;
            if (jg == 0) {
                float4 f;
                f.x = features[(size_t)gg * 3 + 0] * dgg;
                f.y = features[(size_t)gg * 3 + 1] * dgg;
                f.z = features[(size_t)gg * 3 + 2] * dgg;
                f.w = 0.0f;
                *(float4*)rp = f;
            } else {
                int e0 = (jg - 1) * 8;
                uint_t u[4];
                #pragma unroll
                for (int p = 0; p < 4; p++) {
                    float lo = bf16_f(tbuf[e0 + 2 * p][nn]) * dgg;
                    float hi = bf16_f(tbuf[e0 + 2 * p + 1][nn]) * dgg;
                    u[p] = pack_bf16(lo, hi);
                }
                uint4 uv = make_uint4(u[0], u[1], u[2], u[3]);
                *(uint4*)(rp + 16 + (jg - 1) * 16) = uv;
            }
        }
    }
}

__global__ void scan1_kernel(const int* __restrict__ in, int* __restrict__ out,
                             int* __restrict__ bsum, int n) {
    __shared__ int tmp[256];
    int t = threadIdx.x, b = blockIdx.x;
    int base = b * 2048 + t * 8;
    int v[8]; int s = 0;
    #pragma unroll
    for (int q = 0; q < 8; q++) {
        int idx = base + q;
        v[q] = (idx < n) ? in[idx] : 0;
        s += v[q];
    }
    tmp[t] = s; __syncthreads();
    #pragma unroll
    for (int d = 1; d < 256; d <<= 1) {
        int add = (t >= d) ? tmp[t - d] : 0;
        __syncthreads();
        tmp[t] += add;
        __syncthreads();
    }
    int run = tmp[t] - s;
    #pragma unroll
    for (int q = 0; q < 8; q++) {
        int idx = base + q;
        if (idx < n) out[idx] = run;
        run += v[q];
    }
    if (t == 255) bsum[b] = tmp[t];
}

__global__ void scan2_kernel(int* __restrict__ bsum, int B) {
    __shared__ int tmp[512];
    int t = threadIdx.x;
    tmp[t] = (t < B) ? bsum[t] : 0; __syncthreads();
    #pragma unroll
    for (int d = 1; d < 512; d <<= 1) {
        int add = (t >= d) ? tmp[t - d] : 0;
        __syncthreads();
        tmp[t] += add;
        __syncthreads();
    }
    if (t < B) bsum[t] = tmp[t];
}

// scanfix + dinv fused
__global__ void scanfix_dinv_kernel(int* __restrict__ data, const int* __restrict__ bsum,
                                    const int* __restrict__ cnt8, float* __restrict__ dinv,
                                    int n, int Nn) {
    int i = blockIdx.x * 256 + threadIdx.x;
    if (i < n) {
        int b = i >> 11;
        if (b > 0) data[i] += bsum[b - 1];
    }
    if (i < Nn) {
        int s = 0;
        #pragma unroll
        for (int q = 0; q < NSEG; q++) s += cnt8[(size_t)q * Nn + i];
        dinv[i] = rsqrtf((float)s + 1.0f);
    }
}

// octet per node: lane oc walks CSR segment oc [fill8-cnt8, fill8)
__global__ __launch_bounds__(256) void node1g_kernel(
    const int* __restrict__ fill8, const int* __restrict__ cnt8, const int* __restrict__ es,
    const float* __restrict__ dinv, const char* __restrict__ xsb,
    const float* __restrict__ cw1, const float* __restrict__ cb1,
    const float* __restrict__ wb, float* __restrict__ ss, int n)
{
    __shared__ float w[19 * 64];
    __shared__ float bbs[64];
    __shared__ float wes[64];
    for (int i = threadIdx.x; i < 19 * 64; i += 256) w[i] = cw1[i];
    for (int i = threadIdx.x; i < 64; i += 256) { bbs[i] = cb1[i]; wes[i] = wb[i]; }
    __syncthreads();
    const int t  = threadIdx.x;
    const int oc = t & 7;
    const int i  = blockIdx.x * 32 + (t >> 3);
    if (i >= n) return;
    const float di = dinv[i];

    float af[19];
    #pragma unroll
    for (int q = 0; q < 19; q++) af[q] = 0.f;

    auto addrow = [&](const char* rp) {
        float4 F = *(const float4*)rp;
        uint4 U0 = *(const uint4*)(rp + 16);
        uint4 U1 = *(const uint4*)(rp + 32);
        af[0] += F.x; af[1] += F.y; af[2] += F.z;
        af[3]  += blo(U0.x); af[4]  += bhi(U0.x);
        af[5]  += blo(U0.y); af[6]  += bhi(U0.y);
        af[7]  += blo(U0.z); af[8]  += bhi(U0.z);
        af[9]  += blo(U0.w); af[10] += bhi(U0.w);
        af[11] += blo(U1.x); af[12] += bhi(U1.x);
        af[13] += blo(U1.y); af[14] += bhi(U1.y);
        af[15] += blo(U1.z); af[16] += bhi(U1.z);
        af[17] += blo(U1.w); af[18] += bhi(U1.w);
    };

    if (oc == 0) addrow(xsb + (size_t)i * XROW);
    const int end = fill8[(size_t)oc * n + i];
    const int dgs = cnt8[(size_t)oc * n + i];
    for (int e = end - dgs; e < end; e++) {
        int c = es[e];
        addrow(xsb + (size_t)c * XROW);
    }

    float a19[19];
    #pragma unroll
    for (int q = 0; q < 19; q++) {
        float v = af[q];
        v += __shfl_xor(v, 1);
        v += __shfl_xor(v, 2);
        v += __shfl_xor(v, 4);
        a19[q] = v * di;
    }

    const int j0 = oc * 8;
    v2f am[4];
    const v2f* w2  = (const v2f*)w;
    const v2f* bb2 = (const v2f*)bbs;
    #pragma unroll
    for (int q = 0; q < 4; q++) am[q] = bb2[j0 / 2 + q];
    #pragma unroll
    for (int k = 0; k < 19; k++) {
        v2f v = splat2(a19[k]);
        #pragma unroll
        for (int q = 0; q < 4; q++) am[q] = fma2(v, w2[k * 32 + j0 / 2 + q], am[q]);
    }
    const v2f* we2 = (const v2f*)wes;
    v2f sv2 = {0.f, 0.f};
    #pragma unroll
    for (int q = 0; q < 4; q++) sv2 = fma2(max02(am[q]), we2[j0 / 2 + q], sv2);
    float sv = sv2.x + sv2.y;
    sv += __shfl_xor(sv, 1);
    sv += __shfl_xor(sv, 2);
    sv += __shfl_xor(sv, 4);
    if (oc == 0) ss[i] = di * sv;
}

// octet per node: out[i] = b_eff + di * (ss[i] + sum ss[c])
__global__ __launch_bounds__(256) void outg_kernel(
    const int* __restrict__ fill8, const int* __restrict__ cnt8, const int* __restrict__ es,
    const float* __restrict__ dinv, const float* __restrict__ ss,
    const float* __restrict__ wb, float* __restrict__ out, int n)
{
    const int t  = threadIdx.x;
    const int oc = t & 7;
    const int i  = blockIdx.x * 32 + (t >> 3);
    if (i >= n) return;
    const int end = fill8[(size_t)oc * n + i];
    const int dgs = cnt8[(size_t)oc * n + i];
    float sum = (oc == 0) ? ss[i] : 0.f;
    for (int e = end - dgs; e < end; e++) {
        int c = es[e];
        sum += ss[c];
    }
    sum += __shfl_xor(sum, 1);
    sum += __shfl_xor(sum, 2);
    sum += __shfl_xor(sum, 4);
    if (oc == 0) out[i] = wb[64] + dinv[i] * sum;
}

extern "C" void kernel_launch(void* const* d_in, const int* in_sizes, int n_in,
                              void* d_out, int out_size, void* d_ws, size_t ws_size,
                              hipStream_t stream) {
    const float* coords   = (const float*)d_in[0];
    const float* features = (const float*)d_in[1];
    const int*   eidx     = (const int*)d_in[2];
    const float* fw0 = (const float*)d_in[3];
    const float* fb0 = (const float*)d_in[4];
    const float* fg0 = (const float*)d_in[5];
    const float* fe0 = (const float*)d_in[6];
    const float* fw1 = (const float*)d_in[7];
    const float* fb1 = (const float*)d_in[8];
    const float* fg1 = (const float*)d_in[9];
    const float* fe1 = (const float*)d_in[10];
    const float* fw2 = (const float*)d_in[11];
    const float* fb2 = (const float*)d_in[12];
    const float* fg2 = (const float*)d_in[13];
    const float* fe2 = (const float*)d_in[14];
    const float* fw3 = (const float*)d_in[15];
    const float* fb3 = (const float*)d_in[16];
    const float* dw0 = (const float*)d_in[17];
    const float* db0 = (const float*)d_in[18];
    const float* dw1 = (const float*)d_in[19];
    const float* db1 = (const float*)d_in[20];
    const float* dw2 = (const float*)d_in[21];
    const float* db2 = (const float*)d_in[22];
    const float* cw1 = (const float*)d_in[23];
    const float* cb1 = (const float*)d_in[24];
    const float* cw2 = (const float*)d_in[25];
    const float* cb2 = (const float*)d_in[26];
    const float* ow  = (const float*)d_in[27];
    const float* ob  = (const float*)d_in[28];
    float* out = (float*)d_out;

    const int Nn = in_sizes[0] / 2;   // 100000
    const int E_ = in_sizes[2] / 2;   // 2000000
    const int n8 = NSEG * Nn;
    const int NBS = (n8 + 2047) / 2048;
    const int NO = (Nn * 8 + 255) / 256;
    const int NT = (Nn + TM - 1) / TM;
    const int NE = (E_ / 4 + 255) / 256;

    char* ws = (char*)d_ws;
    size_t o = 0;
    char*  xsb   = (char*) (ws + o); o += (size_t)Nn * XROW;
    int*   cnt8  = (int*)  (ws + o); o += (size_t)n8 * sizeof(int);
    int*   fill8 = (int*)  (ws + o); o += (size_t)n8 * sizeof(int);
    int*   bsum  = (int*)  (ws + o); o += 512 * sizeof(int);
    float* dinv  = (float*)(ws + o); o += (size_t)Nn * sizeof(float);
    float* ssb   = (float*)(ws + o); o += (size_t)Nn * sizeof(float);
    int*   es    = (int*)  (ws + o); o += (size_t)E_ * sizeof(int);
    float* wb    = (float*)(ws + o); o += 80 * sizeof(float);
    o = (o + 15) & ~(size_t)15;
    ushort_t* wswz = (ushort_t*)(ws + o); o += 3 * 32768 * sizeof(ushort_t);

    hipMemsetAsync(cnt8, 0, (size_t)n8 * sizeof(int), stream);

    // deg8 + weight-swizzle + wb, one launch
    deg8_prep_kernel<<<NE + 385, 256, 0, stream>>>(eidx, cnt8, E_, Nn, NE,
                                                   fw1, fw2, fw3, wswz,
                                                   cw2, cb2, ow, ob, wb);
    scan1_kernel<<<NBS, 256, 0, stream>>>(cnt8, fill8, bsum, n8);
    scan2_kernel<<<1, 512, 0, stream>>>(bsum, NBS);
    scanfix_dinv_kernel<<<(n8 + 255) / 256, 256, 0, stream>>>(fill8, bsum, cnt8, dinv, n8, Nn);

    // scatter + FFN fused (independent after scanfix; scatter blocks first)
    scatter_ffn_kernel<<<NE + NT, 256, 0, stream>>>(
        eidx, eidx + E_, fill8, es, E_, NE,
        coords, features, dinv,
        fw0, fb0, fg0, fe0,
        wswz,
        fb1, fg1, fe1, fb2, fg2, fe2, fb3,
        dw0, db0, dw1, db1, dw2, db2, xsb, Nn);

    node1g_kernel<<<NO, 256, 0, stream>>>(fill8, cnt8, es, dinv, xsb, cw1, cb1, wb, ssb, Nn);
    outg_kernel<<<NO, 256, 0, stream>>>(fill8, cnt8, es, dinv, ssb, wb, out, Nn);
}